// Round 3
// baseline (958.782 us; speedup 1.0000x reference)
//
#include <hip/hip_runtime.h>

// B=8, T=20, C=1, H=512, W=512
#define FRAMES 160
#define HH 512
#define WW 512
#define STRIPS 16
#define NBLK (STRIPS * FRAMES)   // 2560
#define NTOT 41943040

// ---------------------------------------------------------------------------
// R2: barrier-free wave-local windows with PHASE-DISJOINT register lifetimes.
// R1 spilled (~51MB scratch writes/dispatch, VGPR capped at 84, FETCH 2x):
// all 16 prefetch float4s were held live across the horizontal phase.
// R2 keeps the same verified math but stages loads so live sets never
// overlap: [horiz: acc+prefix] -> [issue new loads] -> [ssim: acc+win+new]
// -> [consume new] -> [issue old loads, consume]. Peak ~115 VGPR -> 4
// waves/SIMD, no spill. No LDS, no barriers in the main loop.
// ---------------------------------------------------------------------------

// SSIM on raw [0,1) values (scale-invariant: C1,C2 divided by 255^2),
// numerator/denominator premultiplied by NP^2 (NP=49). sss = Wxx+Wyy.
__device__ __forceinline__ float ssim_fast(float a, float b, float sss,
                                           float sxy) {
  const float K1 = 0.2401f;        // 2401 * 1e-4
  const float K2 = 2.1609f;        // 2401 * 9e-4
  const float cA = 49.0f / 24.0f;
  const float cB = 49.0f / 48.0f;
  float ab = a * b;
  float s2 = fmaf(a, a, b * b);
  float A1 = fmaf(2.0f, ab, K1);
  float B1 = s2 + K1;
  float A2 = fmaf(cA, fmaf(49.0f, sxy, -ab), K2);
  float B2 = fmaf(cB, fmaf(49.0f, sss, -s2), K2);
  return (A1 * A2) * __builtin_amdgcn_rcpf(B1 * B2);
}

// per-component vertical accumulate / retire
#define ACC1(sx, sy, ss, sp, x_, y_)                  \
  sx += x_; sy += y_;                                 \
  ss = fmaf(x_, x_, ss); ss = fmaf(y_, y_, ss);       \
  sp = fmaf(x_, y_, sp);

#define SUB1(sx, sy, ss, sp, x_, y_)                  \
  sx -= x_; sy -= y_;                                 \
  ss = fmaf(-x_, x_, ss); ss = fmaf(-y_, y_, ss);     \
  sp = fmaf(-x_, y_, sp);

#define ACC4(sx, sy, ss, sp, xv, yv)                  \
  ACC1(sx.x, sy.x, ss.x, sp.x, xv.x, yv.x)            \
  ACC1(sx.y, sy.y, ss.y, sp.y, xv.y, yv.y)            \
  ACC1(sx.z, sy.z, ss.z, sp.z, xv.z, yv.z)            \
  ACC1(sx.w, sy.w, ss.w, sp.w, xv.w, yv.w)

#define SUB4(sx, sy, ss, sp, xv, yv)                  \
  SUB1(sx.x, sy.x, ss.x, sp.x, xv.x, yv.x)            \
  SUB1(sx.y, sy.y, ss.y, sp.y, xv.y, yv.y)            \
  SUB1(sx.z, sy.z, ss.z, sp.z, xv.z, yv.z)            \
  SUB1(sx.w, sy.w, ss.w, sp.w, xv.w, yv.w)

#define LREC4(xv, yv) {                                         \
  float d0_ = xv.x - yv.x, d1_ = xv.y - yv.y,                   \
        d2_ = xv.z - yv.z, d3_ = xv.w - yv.w;                   \
  sabs += (fabsf(d0_) + fabsf(d1_)) + (fabsf(d2_) + fabsf(d3_)); \
  ssq = fmaf(d0_, d0_, ssq); ssq = fmaf(d1_, d1_, ssq);         \
  ssq = fmaf(d2_, d2_, ssq); ssq = fmaf(d3_, d3_, ssq); }

// Horizontal: thread q owns cols 8q..8q+7 of one array held as (lo,hi).
// Prefix p0..p7, neighbor (lane q+1) prefixes n0..n5 via shfl, then the 8
// 7-wide window sums into float4 pair (wa, wb). For q=63 the shuffles
// return garbage but only feed wa.z..wb.w = invalid output cols (>=506),
// masked at accumulation.
#define HORIZ(lo, hi, wa, wb)                         \
  {                                                   \
    float p0 = lo.x;                                  \
    float p1 = p0 + lo.y;                             \
    float p2 = p1 + lo.z;                             \
    float p3 = p2 + lo.w;                             \
    float p4 = p3 + hi.x;                             \
    float p5 = p4 + hi.y;                             \
    float p6 = p5 + hi.z;                             \
    float p7 = p6 + hi.w;                             \
    float n0 = __shfl_down(p0, 1, 64);                \
    float n1 = __shfl_down(p1, 1, 64);                \
    float n2 = __shfl_down(p2, 1, 64);                \
    float n3 = __shfl_down(p3, 1, 64);                \
    float n4 = __shfl_down(p4, 1, 64);                \
    float n5 = __shfl_down(p5, 1, 64);                \
    wa.x = p6;                                        \
    wa.y = p7 - p0;                                   \
    wa.z = (p7 - p1) + n0;                            \
    wa.w = (p7 - p2) + n1;                            \
    wb.x = (p7 - p3) + n2;                            \
    wb.y = (p7 - p4) + n3;                            \
    wb.z = (p7 - p5) + n4;                            \
    wb.w = (p7 - p6) + n5;                            \
  }

// grid (STRIPS, FRAMES), block 128 = two independent 64-lane waves.
// Wave 0 (grp=0): even relative output rows; wave 1: odd rows (slide-by-2).
// Lane q owns cols 8q..8q+7. Strip s covers output rows [32s, 32s+n_out),
// n_out = 32 (s<15) or 26 (s=15). L_rec counting (verified): grp0 counts
// rel rows 0..6 at init and 7..30 on first slide-touch; grp1 counts rel 31.
__global__ __launch_bounds__(128, 4) void fused_kernel(
    const float* __restrict__ gsrc, const float* __restrict__ tsrc,
    float* __restrict__ ws) {
  const int strip = blockIdx.x;
  const int frame = blockIdx.y;
  const int row0 = strip * 32;
  const int n_iter = (strip == STRIPS - 1) ? 13 : 16;  // output-row pairs
  const int tid = threadIdx.x;
  const int grp = tid >> 6;
  const int q = tid & 63;

  const float* gp = gsrc + ((size_t)frame * HH + row0 + grp) * WW + q * 8;
  const float* tp = tsrc + ((size_t)frame * HH + row0 + grp) * WW + q * 8;

  const float4 z4 = make_float4(0.f, 0.f, 0.f, 0.f);
  float4 Sx0 = z4, Sx1 = z4, Sy0 = z4, Sy1 = z4;
  float4 Ss0 = z4, Ss1 = z4, Sp0 = z4, Sp1 = z4;   // Ss = Sxx+Syy, Sp = Sxy
  float sabs = 0.f, ssq = 0.f, ssum = 0.f;

  // init window: rel rows grp..grp+6 (grp0's rows 0..6 all L_rec-counted)
  #pragma unroll
  for (int i = 0; i < 7; ++i) {
    float4 xa = *(const float4*)(gp + (size_t)i * WW);
    float4 xb = *(const float4*)(gp + (size_t)i * WW + 4);
    float4 ya = *(const float4*)(tp + (size_t)i * WW);
    float4 yb = *(const float4*)(tp + (size_t)i * WW + 4);
    ACC4(Sx0, Sy0, Ss0, Sp0, xa, ya)
    ACC4(Sx1, Sy1, Ss1, Sp1, xb, yb)
    if (grp == 0) { LREC4(xa, ya) LREC4(xb, yb) }
  }

  #pragma unroll 1
  for (int it = 0; it < n_iter; ++it) {
    const bool slide = (it + 1 < n_iter);

    // ---- phase 1: horizontal 7-windows, wave-local (no LDS/barriers) ----
    float4 WXa, WXb, WYa, WYb, WSa, WSb, WPa, WPb;
    HORIZ(Sx0, Sx1, WXa, WXb)
    HORIZ(Sy0, Sy1, WYa, WYb)
    HORIZ(Ss0, Ss1, WSa, WSb)
    HORIZ(Sp0, Sp1, WPa, WPb)

    // ---- phase 2: issue NEW-row loads (prefix temps now dead) ----
    float4 nx0a, nx0b, ny0a, ny0b, nx1a, nx1b, ny1a, ny1b;
    if (slide) {
      const float* pn = gp + (size_t)(2 * it + 7) * WW;
      const float* qn = tp + (size_t)(2 * it + 7) * WW;
      nx0a = *(const float4*)pn;
      nx0b = *(const float4*)(pn + 4);
      ny0a = *(const float4*)qn;
      ny0b = *(const float4*)(qn + 4);
      nx1a = *(const float4*)(pn + WW);
      nx1b = *(const float4*)(pn + WW + 4);
      ny1a = *(const float4*)(qn + WW);
      ny1b = *(const float4*)(qn + WW + 4);
    }

    // ---- phase 3: ssim on the windows (covers part of load latency) ----
    float s01 = ssim_fast(WXa.x, WYa.x, WSa.x, WPa.x) +
                ssim_fast(WXa.y, WYa.y, WSa.y, WPa.y);
    float vr = ((ssim_fast(WXa.z, WYa.z, WSa.z, WPa.z) +
                 ssim_fast(WXa.w, WYa.w, WSa.w, WPa.w)) +
                (ssim_fast(WXb.x, WYb.x, WSb.x, WPb.x) +
                 ssim_fast(WXb.y, WYb.y, WSb.y, WPb.y))) +
               (ssim_fast(WXb.z, WYb.z, WSb.z, WPb.z) +
                ssim_fast(WXb.w, WYb.w, WSb.w, WPb.w));
    // valid output cols: 8q+j <= 505. q<63: all 8 valid; q=63: j<2 only.
    // select-then-add is NaN-safe against shuffle garbage in lane 63.
    ssum += s01;
    ssum += (q < 63) ? vr : 0.f;

    if (slide) {
      // ---- phase 4: consume new rows (windows now dead) ----
      ACC4(Sx0, Sy0, Ss0, Sp0, nx0a, ny0a)
      ACC4(Sx1, Sy1, Ss1, Sp1, nx0b, ny0b)
      if ((grp == 0) && (2 * it + 7 <= 30)) { LREC4(nx0a, ny0a) LREC4(nx0b, ny0b) }
      ACC4(Sx0, Sy0, Ss0, Sp0, nx1a, ny1a)
      ACC4(Sx1, Sy1, Ss1, Sp1, nx1b, ny1b)
      bool cnt = (grp == 0) ? (2 * it + 8 <= 30) : (2 * it + 9 == 31);
      if (cnt) { LREC4(nx1a, ny1a) LREC4(nx1b, ny1b) }

      // ---- phase 5: OLD-row loads (L2-hot re-reads) + retire ----
      const float* po = gp + (size_t)(2 * it) * WW;
      const float* qo = tp + (size_t)(2 * it) * WW;
      float4 ox0a = *(const float4*)po;
      float4 ox0b = *(const float4*)(po + 4);
      float4 oy0a = *(const float4*)qo;
      float4 oy0b = *(const float4*)(qo + 4);
      float4 ox1a = *(const float4*)(po + WW);
      float4 ox1b = *(const float4*)(po + WW + 4);
      float4 oy1a = *(const float4*)(qo + WW);
      float4 oy1b = *(const float4*)(qo + WW + 4);
      SUB4(Sx0, Sy0, Ss0, Sp0, ox0a, oy0a)
      SUB4(Sx1, Sy1, Ss1, Sp1, ox0b, oy0b)
      SUB4(Sx0, Sy0, Ss0, Sp0, ox1a, oy1a)
      SUB4(Sx1, Sy1, Ss1, Sp1, ox1b, oy1b)
    }
  }

  // block reduce sabs / ssq / ssum (2 waves)
  #pragma unroll
  for (int off = 32; off > 0; off >>= 1) {
    sabs += __shfl_down(sabs, off, 64);
    ssq += __shfl_down(ssq, off, 64);
    ssum += __shfl_down(ssum, off, 64);
  }
  __shared__ float scr[6];
  if (q == 0) { scr[grp] = sabs; scr[2 + grp] = ssq; scr[4 + grp] = ssum; }
  __syncthreads();
  if (tid == 0) {
    const int bid = blockIdx.y * STRIPS + blockIdx.x;
    ws[bid] = scr[0] + scr[1];
    ws[NBLK + bid] = scr[2] + scr[3];
    ws[2 * NBLK + bid] = scr[4] + scr[5];
  }
}

__global__ __launch_bounds__(256) void finalize_kernel(
    const float* __restrict__ ws, const float* __restrict__ genD,
    float* __restrict__ out) {
  const int tid = threadIdx.x;
  float a = 0.f, b = 0.f, c = 0.f;
  for (int i = tid; i < NBLK; i += 256) {
    a += ws[i];
    b += ws[NBLK + i];
    c += ws[2 * NBLK + i];
  }
  #pragma unroll
  for (int off = 32; off > 0; off >>= 1) {
    a += __shfl_down(a, off, 64);
    b += __shfl_down(b, off, 64);
    c += __shfl_down(c, off, 64);
  }
  __shared__ float la[4], lb[4], lc[4];
  const int lane = tid & 63, wv = tid >> 6;
  if (lane == 0) { la[wv] = a; lb[wv] = b; lc[wv] = c; }
  __syncthreads();
  if (tid == 0) {
    a = la[0] + la[1] + la[2] + la[3];
    b = lb[0] + lb[1] + lb[2] + lb[3];
    c = lc[0] + lc[1] + lc[2] + lc[3];
    const float invN = 1.0f / (float)NTOT;
    float L_rec = a * invN + b * invN;
    float L_ssim = c / (160.0f * 506.0f * 506.0f);
    float d = 0.f;
    #pragma unroll
    for (int i = 0; i < 8; ++i) d += genD[i];
    float L_adv = -d / 8.0f;
    float L_total = L_rec + 0.01f * (1.0f - L_ssim) + 0.0001f * L_adv;
    out[0] = L_total;
    out[1] = L_rec;
    out[2] = L_ssim;
    out[3] = L_adv;
  }
}

extern "C" void kernel_launch(void* const* d_in, const int* in_sizes, int n_in,
                              void* d_out, int out_size, void* d_ws,
                              size_t ws_size, hipStream_t stream) {
  const float* gen_img = (const float*)d_in[0];
  const float* target = (const float*)d_in[1];
  const float* gen_D = (const float*)d_in[2];
  float* out = (float*)d_out;
  float* ws = (float*)d_ws;

  dim3 grid(STRIPS, FRAMES);
  fused_kernel<<<grid, 128, 0, stream>>>(gen_img, target, ws);
  finalize_kernel<<<1, 256, 0, stream>>>(ws, gen_D, out);
}

// Round 4
// 418.607 us; speedup vs baseline: 2.2904x; 2.2904x over previous
//
#include <hip/hip_runtime.h>

// B=8, T=20, C=1, H=512, W=512
#define FRAMES 160
#define HH 512
#define WW 512
#define STRIPS 16
#define NBLK (STRIPS * FRAMES)   // 2560
#define NTOT 41943040

// ---------------------------------------------------------------------------
// R3: R2 + occupancy cap. R1/R2 both spilled massively (R2: 1.03GB scratch
// writes, VGPR_Count=64=512/8): the AMDGPU backend's memory-bound heuristic
// targets MAX occupancy (8 waves/EU -> 64 VGPRs) and spills to get there;
// launch_bounds' 2nd arg only sets the MINIMUM. amdgpu_waves_per_eu(2,4)
// caps the target at 4 waves/EU -> 128-VGPR budget -> the ~110-reg live set
// (32 acc + 32 prefetch + 32 windows + temps) fits with zero spill.
// New-row prefetch issued before the horizontal phase (~400cy of shuffle+
// ssim VALU work hides HBM latency). No LDS, no barriers in the main loop.
// ---------------------------------------------------------------------------

// SSIM on raw [0,1) values (scale-invariant: C1,C2 divided by 255^2),
// numerator/denominator premultiplied by NP^2 (NP=49). sss = Wxx+Wyy.
__device__ __forceinline__ float ssim_fast(float a, float b, float sss,
                                           float sxy) {
  const float K1 = 0.2401f;        // 2401 * 1e-4
  const float K2 = 2.1609f;        // 2401 * 9e-4
  const float cA = 49.0f / 24.0f;
  const float cB = 49.0f / 48.0f;
  float ab = a * b;
  float s2 = fmaf(a, a, b * b);
  float A1 = fmaf(2.0f, ab, K1);
  float B1 = s2 + K1;
  float A2 = fmaf(cA, fmaf(49.0f, sxy, -ab), K2);
  float B2 = fmaf(cB, fmaf(49.0f, sss, -s2), K2);
  return (A1 * A2) * __builtin_amdgcn_rcpf(B1 * B2);
}

// per-component vertical accumulate / retire
#define ACC1(sx, sy, ss, sp, x_, y_)                  \
  sx += x_; sy += y_;                                 \
  ss = fmaf(x_, x_, ss); ss = fmaf(y_, y_, ss);       \
  sp = fmaf(x_, y_, sp);

#define SUB1(sx, sy, ss, sp, x_, y_)                  \
  sx -= x_; sy -= y_;                                 \
  ss = fmaf(-x_, x_, ss); ss = fmaf(-y_, y_, ss);     \
  sp = fmaf(-x_, y_, sp);

#define ACC4(sx, sy, ss, sp, xv, yv)                  \
  ACC1(sx.x, sy.x, ss.x, sp.x, xv.x, yv.x)            \
  ACC1(sx.y, sy.y, ss.y, sp.y, xv.y, yv.y)            \
  ACC1(sx.z, sy.z, ss.z, sp.z, xv.z, yv.z)            \
  ACC1(sx.w, sy.w, ss.w, sp.w, xv.w, yv.w)

#define SUB4(sx, sy, ss, sp, xv, yv)                  \
  SUB1(sx.x, sy.x, ss.x, sp.x, xv.x, yv.x)            \
  SUB1(sx.y, sy.y, ss.y, sp.y, xv.y, yv.y)            \
  SUB1(sx.z, sy.z, ss.z, sp.z, xv.z, yv.z)            \
  SUB1(sx.w, sy.w, ss.w, sp.w, xv.w, yv.w)

#define LREC4(xv, yv) {                                         \
  float d0_ = xv.x - yv.x, d1_ = xv.y - yv.y,                   \
        d2_ = xv.z - yv.z, d3_ = xv.w - yv.w;                   \
  sabs += (fabsf(d0_) + fabsf(d1_)) + (fabsf(d2_) + fabsf(d3_)); \
  ssq = fmaf(d0_, d0_, ssq); ssq = fmaf(d1_, d1_, ssq);         \
  ssq = fmaf(d2_, d2_, ssq); ssq = fmaf(d3_, d3_, ssq); }

// Horizontal: thread q owns cols 8q..8q+7 of one array held as (lo,hi).
// Prefix p0..p7, neighbor (lane q+1) prefixes n0..n5 via shfl, then the 8
// 7-wide window sums into float4 pair (wa, wb). For q=63 the shuffles
// return garbage but only feed wa.z..wb.w = invalid output cols (>=506),
// masked at accumulation.
#define HORIZ(lo, hi, wa, wb)                         \
  {                                                   \
    float p0 = lo.x;                                  \
    float p1 = p0 + lo.y;                             \
    float p2 = p1 + lo.z;                             \
    float p3 = p2 + lo.w;                             \
    float p4 = p3 + hi.x;                             \
    float p5 = p4 + hi.y;                             \
    float p6 = p5 + hi.z;                             \
    float p7 = p6 + hi.w;                             \
    float n0 = __shfl_down(p0, 1, 64);                \
    float n1 = __shfl_down(p1, 1, 64);                \
    float n2 = __shfl_down(p2, 1, 64);                \
    float n3 = __shfl_down(p3, 1, 64);                \
    float n4 = __shfl_down(p4, 1, 64);                \
    float n5 = __shfl_down(p5, 1, 64);                \
    wa.x = p6;                                        \
    wa.y = p7 - p0;                                   \
    wa.z = (p7 - p1) + n0;                            \
    wa.w = (p7 - p2) + n1;                            \
    wb.x = (p7 - p3) + n2;                            \
    wb.y = (p7 - p4) + n3;                            \
    wb.z = (p7 - p5) + n4;                            \
    wb.w = (p7 - p6) + n5;                            \
  }

// grid (STRIPS, FRAMES), block 128 = two independent 64-lane waves.
// Wave 0 (grp=0): even relative output rows; wave 1: odd rows (slide-by-2).
// Lane q owns cols 8q..8q+7. Strip s covers output rows [32s, 32s+n_out),
// n_out = 32 (s<15) or 26 (s=15). L_rec counting (verified): grp0 counts
// rel rows 0..6 at init and 7..30 on first slide-touch; grp1 counts rel 31.
__global__ __launch_bounds__(128)
__attribute__((amdgpu_waves_per_eu(2, 4)))
void fused_kernel(
    const float* __restrict__ gsrc, const float* __restrict__ tsrc,
    float* __restrict__ ws) {
  const int strip = blockIdx.x;
  const int frame = blockIdx.y;
  const int row0 = strip * 32;
  const int n_iter = (strip == STRIPS - 1) ? 13 : 16;  // output-row pairs
  const int tid = threadIdx.x;
  const int grp = tid >> 6;
  const int q = tid & 63;

  const float* gp = gsrc + ((size_t)frame * HH + row0 + grp) * WW + q * 8;
  const float* tp = tsrc + ((size_t)frame * HH + row0 + grp) * WW + q * 8;

  const float4 z4 = make_float4(0.f, 0.f, 0.f, 0.f);
  float4 Sx0 = z4, Sx1 = z4, Sy0 = z4, Sy1 = z4;
  float4 Ss0 = z4, Ss1 = z4, Sp0 = z4, Sp1 = z4;   // Ss = Sxx+Syy, Sp = Sxy
  float sabs = 0.f, ssq = 0.f, ssum = 0.f;

  // init window: rel rows grp..grp+6 (grp0's rows 0..6 all L_rec-counted)
  #pragma unroll
  for (int i = 0; i < 7; ++i) {
    float4 xa = *(const float4*)(gp + (size_t)i * WW);
    float4 xb = *(const float4*)(gp + (size_t)i * WW + 4);
    float4 ya = *(const float4*)(tp + (size_t)i * WW);
    float4 yb = *(const float4*)(tp + (size_t)i * WW + 4);
    ACC4(Sx0, Sy0, Ss0, Sp0, xa, ya)
    ACC4(Sx1, Sy1, Ss1, Sp1, xb, yb)
    if (grp == 0) { LREC4(xa, ya) LREC4(xb, yb) }
  }

  #pragma unroll 1
  for (int it = 0; it < n_iter; ++it) {
    const bool slide = (it + 1 < n_iter);

    // ---- issue NEW-row loads first: HORIZ+ssim (~400cy VALU) hides HBM ----
    float4 nx0a, nx0b, ny0a, ny0b, nx1a, nx1b, ny1a, ny1b;
    if (slide) {
      const float* pn = gp + (size_t)(2 * it + 7) * WW;
      const float* qn = tp + (size_t)(2 * it + 7) * WW;
      nx0a = *(const float4*)pn;
      nx0b = *(const float4*)(pn + 4);
      ny0a = *(const float4*)qn;
      ny0b = *(const float4*)(qn + 4);
      nx1a = *(const float4*)(pn + WW);
      nx1b = *(const float4*)(pn + WW + 4);
      ny1a = *(const float4*)(qn + WW);
      ny1b = *(const float4*)(qn + WW + 4);
    }

    // ---- horizontal 7-windows, wave-local (no LDS/barriers) ----
    float4 WXa, WXb, WYa, WYb, WSa, WSb, WPa, WPb;
    HORIZ(Sx0, Sx1, WXa, WXb)
    HORIZ(Sy0, Sy1, WYa, WYb)
    HORIZ(Ss0, Ss1, WSa, WSb)
    HORIZ(Sp0, Sp1, WPa, WPb)

    // ---- ssim on the windows ----
    float s01 = ssim_fast(WXa.x, WYa.x, WSa.x, WPa.x) +
                ssim_fast(WXa.y, WYa.y, WSa.y, WPa.y);
    float vr = ((ssim_fast(WXa.z, WYa.z, WSa.z, WPa.z) +
                 ssim_fast(WXa.w, WYa.w, WSa.w, WPa.w)) +
                (ssim_fast(WXb.x, WYb.x, WSb.x, WPb.x) +
                 ssim_fast(WXb.y, WYb.y, WSb.y, WPb.y))) +
               (ssim_fast(WXb.z, WYb.z, WSb.z, WPb.z) +
                ssim_fast(WXb.w, WYb.w, WSb.w, WPb.w));
    // valid output cols: 8q+j <= 505. q<63: all 8 valid; q=63: j<2 only.
    // select-then-add is NaN-safe against shuffle garbage in lane 63.
    ssum += s01;
    ssum += (q < 63) ? vr : 0.f;

    if (slide) {
      // ---- consume new rows (windows now dead) ----
      ACC4(Sx0, Sy0, Ss0, Sp0, nx0a, ny0a)
      ACC4(Sx1, Sy1, Ss1, Sp1, nx0b, ny0b)
      if ((grp == 0) && (2 * it + 7 <= 30)) { LREC4(nx0a, ny0a) LREC4(nx0b, ny0b) }
      ACC4(Sx0, Sy0, Ss0, Sp0, nx1a, ny1a)
      ACC4(Sx1, Sy1, Ss1, Sp1, nx1b, ny1b)
      bool cnt = (grp == 0) ? (2 * it + 8 <= 30) : (2 * it + 9 == 31);
      if (cnt) { LREC4(nx1a, ny1a) LREC4(nx1b, ny1b) }

      // ---- OLD-row loads (L2-hot re-reads) + retire ----
      const float* po = gp + (size_t)(2 * it) * WW;
      const float* qo = tp + (size_t)(2 * it) * WW;
      float4 ox0a = *(const float4*)po;
      float4 ox0b = *(const float4*)(po + 4);
      float4 oy0a = *(const float4*)qo;
      float4 oy0b = *(const float4*)(qo + 4);
      float4 ox1a = *(const float4*)(po + WW);
      float4 ox1b = *(const float4*)(po + WW + 4);
      float4 oy1a = *(const float4*)(qo + WW);
      float4 oy1b = *(const float4*)(qo + WW + 4);
      SUB4(Sx0, Sy0, Ss0, Sp0, ox0a, oy0a)
      SUB4(Sx1, Sy1, Ss1, Sp1, ox0b, oy0b)
      SUB4(Sx0, Sy0, Ss0, Sp0, ox1a, oy1a)
      SUB4(Sx1, Sy1, Ss1, Sp1, ox1b, oy1b)
    }
  }

  // block reduce sabs / ssq / ssum (2 waves)
  #pragma unroll
  for (int off = 32; off > 0; off >>= 1) {
    sabs += __shfl_down(sabs, off, 64);
    ssq += __shfl_down(ssq, off, 64);
    ssum += __shfl_down(ssum, off, 64);
  }
  __shared__ float scr[6];
  if (q == 0) { scr[grp] = sabs; scr[2 + grp] = ssq; scr[4 + grp] = ssum; }
  __syncthreads();
  if (tid == 0) {
    const int bid = blockIdx.y * STRIPS + blockIdx.x;
    ws[bid] = scr[0] + scr[1];
    ws[NBLK + bid] = scr[2] + scr[3];
    ws[2 * NBLK + bid] = scr[4] + scr[5];
  }
}

__global__ __launch_bounds__(256) void finalize_kernel(
    const float* __restrict__ ws, const float* __restrict__ genD,
    float* __restrict__ out) {
  const int tid = threadIdx.x;
  float a = 0.f, b = 0.f, c = 0.f;
  for (int i = tid; i < NBLK; i += 256) {
    a += ws[i];
    b += ws[NBLK + i];
    c += ws[2 * NBLK + i];
  }
  #pragma unroll
  for (int off = 32; off > 0; off >>= 1) {
    a += __shfl_down(a, off, 64);
    b += __shfl_down(b, off, 64);
    c += __shfl_down(c, off, 64);
  }
  __shared__ float la[4], lb[4], lc[4];
  const int lane = tid & 63, wv = tid >> 6;
  if (lane == 0) { la[wv] = a; lb[wv] = b; lc[wv] = c; }
  __syncthreads();
  if (tid == 0) {
    a = la[0] + la[1] + la[2] + la[3];
    b = lb[0] + lb[1] + lb[2] + lb[3];
    c = lc[0] + lc[1] + lc[2] + lc[3];
    const float invN = 1.0f / (float)NTOT;
    float L_rec = a * invN + b * invN;
    float L_ssim = c / (160.0f * 506.0f * 506.0f);
    float d = 0.f;
    #pragma unroll
    for (int i = 0; i < 8; ++i) d += genD[i];
    float L_adv = -d / 8.0f;
    float L_total = L_rec + 0.01f * (1.0f - L_ssim) + 0.0001f * L_adv;
    out[0] = L_total;
    out[1] = L_rec;
    out[2] = L_ssim;
    out[3] = L_adv;
  }
}

extern "C" void kernel_launch(void* const* d_in, const int* in_sizes, int n_in,
                              void* d_out, int out_size, void* d_ws,
                              size_t ws_size, hipStream_t stream) {
  const float* gen_img = (const float*)d_in[0];
  const float* target = (const float*)d_in[1];
  const float* gen_D = (const float*)d_in[2];
  float* out = (float*)d_out;
  float* ws = (float*)d_ws;

  dim3 grid(STRIPS, FRAMES);
  fused_kernel<<<grid, 128, 0, stream>>>(gen_img, target, ws);
  finalize_kernel<<<1, 256, 0, stream>>>(ws, gen_D, out);
}